// Round 9
// baseline (65290.173 us; speedup 1.0000x reference)
//
#include <hip/hip_runtime.h>
#include <cmath>

#define NN   68     // nodes
#define CH   20     // padded floats per 4-way K-chunk (17 real + 3 pad)
#define NPAD 80     // 4*CH float2 pairs per buffer
#define NT   256    // 4 full waves

// quad_perm DPP: xor1 = 0xB1, xor2 = 0x4E (pure VALU cross-lane in a quad)
template <int CTRL>
__device__ __forceinline__ float dppf(float x) {
    return __int_as_float(
        __builtin_amdgcn_mov_dpp(__float_as_int(x), CTRL, 0xF, 0xF, true));
}

#if __has_builtin(__builtin_amdgcn_exp2f)
#define FAST_EXP2(x) __builtin_amdgcn_exp2f(x)
#else
#define FAST_EXP2(x) exp2f(x)
#endif
#define FAST_RCP(x) __builtin_amdgcn_rcpf(x)

// interleaved MAC: pair buffer holds (A=E_{t-1}, B=E_t) interleaved, so the
// float4 pair (vA,vB) covers K-elements 4m..4m+3 of BOTH vectors.
// c.x<->k=4m (vA.x A, vA.y B), c.y<->4m+1 (vA.z/.w), c.z<->4m+2, c.w<->4m+3
#define MACP(c, vA, vB)               \
    a0 = fmaf(c.x, vA.x, a0);         \
    b0 = fmaf(c.x, vA.y, b0);         \
    a1 = fmaf(c.y, vA.z, a1);         \
    b1 = fmaf(c.y, vA.w, b1);         \
    a2 = fmaf(c.z, vB.x, a2);         \
    b2 = fmaf(c.z, vB.y, b2);         \
    a3 = fmaf(c.w, vB.z, a3);         \
    b3 = fmaf(c.w, vB.w, b3);

// one Euler sub-step, fully hand-fma'd (R4-validated fast exp2/rcp path)
#define ELEM(Ein, Iin, CONN, Eout, Iout)                                      \
    {                                                                         \
        const float xE_ = fmaf(P5, (CONN),                                    \
                               fmaf(P1, (Ein), fmaf(-P2, (Iin), Pp)));        \
        const float SE_ = FAST_RCP(1.0f + FAST_EXP2(fmaf(kE2, xE_, bE2)));    \
        const float xI_ = fmaf(P3, (Ein), -(P4 * (Iin)));                     \
        const float SI_ = FAST_RCP(1.0f + FAST_EXP2(fmaf(kI2, xI_, bI2)));    \
        Eout = fmaf(fmaf(kE - (Ein), SE_ - s0E, -(Ein)), inv_te, (Ein));      \
        Iout = fmaf(fmaf(kI - (Iin), SI_ - s0I, -(Iin)), inv_ti, (Iin));      \
    }

// SUPERSTEP: steps T,T+1, ONE barrier. RBUF holds pairs (E_{T-1}, E_T);
// writes (E_{T+1}, E_{T+2}) into WBUF. Extras (node 64+w) ride on lanes 0..3
// of each wave, reusing the SAME loaded v-quads (zero extra LDS traffic).
#define SUPER(RBUF, WBUF, D1, D2, X1, X2)                                     \
    {                                                                         \
        const float4* vp = (const float4*)&(RBUF)[CH * s];                    \
        const float4 v0 = vp[0], v1 = vp[1], v2 = vp[2], v3 = vp[3],          \
                     v4 = vp[4], v5 = vp[5], v6 = vp[6], v7 = vp[7],          \
                     v8 = vp[8], v9 = vp[9];                                  \
        {                                                                     \
            float a0=0.f,a1=0.f,a2=0.f,a3=0.f,b0=0.f,b1=0.f,b2=0.f,b3=0.f;    \
            MACP(c0, v0, v1) MACP(c1, v2, v3) MACP(c2, v4, v5)                \
            MACP(c3, v6, v7) MACP(c4, v8, v9)                                 \
            float pA = (a0 + a1) + (a2 + a3);                                 \
            float pB = (b0 + b1) + (b2 + b3);                                 \
            pA += dppf<0xB1>(pA); pA += dppf<0x4E>(pA);                       \
            pB += dppf<0xB1>(pB); pB += dppf<0x4E>(pB);                       \
            float En1, In1, En2, In2;                                         \
            ELEM(E, I, pA, En1, In1)                                          \
            ELEM(En1, In1, pB, En2, In2)                                      \
            if (s == 0) (WBUF)[j] = make_float2(En1, En2);                    \
            D1 = En1 - In1; D2 = En2 - In2;                                   \
            E = En2; I = In2;                                                 \
        }                                                                     \
        if (ln < 4) {                                                         \
            float a0=0.f,a1=0.f,a2=0.f,a3=0.f,b0=0.f,b1=0.f,b2=0.f,b3=0.f;    \
            MACP(x0, v0, v1) MACP(x1, v2, v3) MACP(x2, v4, v5)                \
            MACP(x3, v6, v7) MACP(x4, v8, v9)                                 \
            float pA = (a0 + a1) + (a2 + a3);                                 \
            float pB = (b0 + b1) + (b2 + b3);                                 \
            pA += dppf<0xB1>(pA); pA += dppf<0x4E>(pA);                       \
            pB += dppf<0xB1>(pB); pB += dppf<0x4E>(pB);                       \
            float F1, G1, F2, G2;                                             \
            ELEM(E2, I2, pA, F1, G1)                                          \
            ELEM(F1, G1, pB, F2, G2)                                          \
            if (ln == 0) (WBUF)[64 + w] = make_float2(F1, F2);                \
            X1 = F1 - G1; X2 = F2 - G2;                                       \
            E2 = F2; I2 = G2;                                                 \
        }                                                                     \
        asm volatile("s_waitcnt lgkmcnt(0)\ns_barrier" ::: "memory");         \
    }

__global__ __launch_bounds__(NT, 1)
void nmm_kernel(const float* __restrict__ params,
                const float* __restrict__ Cjk,
                const float* __restrict__ y0,
                float* __restrict__ out,
                const int num_steps)
{
#pragma clang fp contract(off)
    const int tid = threadIdx.x;
    const int j   = tid >> 2;     // primary node 0..63 (lanes 4j..4j+3)
    const int s   = tid & 3;      // K-chunk 0..3
    const int w   = tid >> 6;     // wave 0..3 -> extra node 64+w
    const int ln  = tid & 63;     // lane in wave

    // interleaved state pairs (x = older E, y = newer E), double-buffered
    __shared__ __align__(16) float2 Pb0[NPAD], Pb1[NPAD];

    const float tau_e = params[0], tau_i = params[1];
    const float P1 = params[2], P2 = params[3], P3 = params[4];
    const float P4 = params[5], P5 = params[6], Pp = params[7];
    const float kE = params[8], kI = params[9];

    const float LOG2E = 1.4426950408889634f;
    const float kE2 = -1.3f * LOG2E, bE2 = (1.3f * 4.0f) * LOG2E;
    const float kI2 = -2.0f * LOG2E, bI2 = (2.0f * 3.7f) * LOG2E;
    const float s0E = 1.0f / (1.0f + expf(5.2f));
    const float s0I = 1.0f / (1.0f + expf(7.4f));
    const float inv_te = 1.0f / tau_e, inv_ti = 1.0f / tau_i;

    const float4 z4 = make_float4(0.f, 0.f, 0.f, 0.f);

    // primary C row j, chunk s: 5 quads, guarded (17 real quads per row)
    const float* crow = Cjk + j * NN + CH * s;
    const int g0 = 5 * s;
    const float4 c0 = (g0 + 0 < 17) ? *(const float4*)(crow +  0) : z4;
    const float4 c1 = (g0 + 1 < 17) ? *(const float4*)(crow +  4) : z4;
    const float4 c2 = (g0 + 2 < 17) ? *(const float4*)(crow +  8) : z4;
    const float4 c3 = (g0 + 3 < 17) ? *(const float4*)(crow + 12) : z4;
    const float4 c4 = (g0 + 4 < 17) ? *(const float4*)(crow + 16) : z4;

    // extra C row 64+w, chunk ln (only lanes ln<4 load real data)
    const float* xrow = Cjk + (64 + w) * NN + CH * ln;
    const int gx = 5 * ln;
    const bool xa = (ln < 4);
    const float4 x0 = (xa && gx + 0 < 17) ? *(const float4*)(xrow +  0) : z4;
    const float4 x1 = (xa && gx + 1 < 17) ? *(const float4*)(xrow +  4) : z4;
    const float4 x2 = (xa && gx + 2 < 17) ? *(const float4*)(xrow +  8) : z4;
    const float4 x3 = (xa && gx + 3 < 17) ? *(const float4*)(xrow + 12) : z4;
    const float4 x4 = (xa && gx + 4 < 17) ? *(const float4*)(xrow + 16) : z4;

    // init pairs: reference's step 0 AND 1 both use C@E_0 -> pair0=(E0,E0);
    // pads 68..79 zero in both buffers, never written again
    if (tid < NPAD) {
        const float v = (tid < NN) ? y0[tid] : 0.0f;
        Pb0[tid] = make_float2(v, v);
    } else if (tid < 2 * NPAD) {
        Pb1[tid - NPAD] = make_float2(0.f, 0.f);
    }

    float E  = y0[j];
    float I  = y0[NN + j];
    float E2 = y0[64 + w];
    float I2 = y0[NN + 64 + w];
    asm volatile("s_waitcnt lgkmcnt(0)\ns_barrier" ::: "memory");

    float* op = out + (size_t)j * (size_t)num_steps;
    float* ox = out + (size_t)(64 + w) * (size_t)num_steps;

    int t = 0;
    for (; t + 3 < num_steps; t += 4) {
        float d0, d1, d2, d3;
        float e0v = 0.f, e1v = 0.f, e2v = 0.f, e3v = 0.f;
        SUPER(Pb0, Pb1, d0, d1, e0v, e1v)
        SUPER(Pb1, Pb0, d2, d3, e2v, e3v)
        if (s == 0)  *(float4*)(op + t) = make_float4(d0, d1, d2, d3);
        if (ln == 0) *(float4*)(ox + t) = make_float4(e0v, e1v, e2v, e3v);
    }
    // generic tails (dead for num_steps % 4 == 0, kept for correctness)
    bool rb1 = false;
    if (t + 1 < num_steps) {
        float d0, d1, e0v = 0.f, e1v = 0.f;
        SUPER(Pb0, Pb1, d0, d1, e0v, e1v)
        if (s == 0)  *(float2*)(op + t) = make_float2(d0, d1);
        if (ln == 0) *(float2*)(ox + t) = make_float2(e0v, e1v);
        t += 2; rb1 = true;
    }
    if (t < num_steps) {   // final odd step: conn_t = C @ E_{t-1} = pair .x
        const float2* R = rb1 ? Pb1 : Pb0;
        const float4* vp = (const float4*)&R[CH * s];
        const float4 v0 = vp[0], v1 = vp[1], v2 = vp[2], v3 = vp[3],
                     v4 = vp[4], v5 = vp[5], v6 = vp[6], v7 = vp[7],
                     v8 = vp[8], v9 = vp[9];
        float a0 = 0.f, a1 = 0.f, a2 = 0.f, a3 = 0.f;
#define MACA(c, vA, vB)               \
        a0 = fmaf(c.x, vA.x, a0);     \
        a1 = fmaf(c.y, vA.z, a1);     \
        a2 = fmaf(c.z, vB.x, a2);     \
        a3 = fmaf(c.w, vB.z, a3);
        MACA(c0, v0, v1) MACA(c1, v2, v3) MACA(c2, v4, v5)
        MACA(c3, v6, v7) MACA(c4, v8, v9)
        float pA = (a0 + a1) + (a2 + a3);
        pA += dppf<0xB1>(pA); pA += dppf<0x4E>(pA);
        float En1, In1;
        ELEM(E, I, pA, En1, In1)
        if (s == 0) op[t] = En1 - In1;
        if (ln < 4) {
            float b0 = 0.f, b1 = 0.f, b2 = 0.f, b3 = 0.f;
            float a0 = 0.f, a1 = 0.f, a2 = 0.f, a3 = 0.f;
            (void)b0; (void)b1; (void)b2; (void)b3;
            MACA(x0, v0, v1) MACA(x1, v2, v3) MACA(x2, v4, v5)
            MACA(x3, v6, v7) MACA(x4, v8, v9)
            float pX = (a0 + a1) + (a2 + a3);
            pX += dppf<0xB1>(pX); pX += dppf<0x4E>(pX);
            float F1, G1;
            ELEM(E2, I2, pX, F1, G1)
            if (ln == 0) ox[t] = F1 - G1;
        }
#undef MACA
    }
}

extern "C" void kernel_launch(void* const* d_in, const int* in_sizes, int n_in,
                              void* d_out, int out_size, void* d_ws, size_t ws_size,
                              hipStream_t stream) {
    const float* params = (const float*)d_in[0];
    const float* Cjk    = (const float*)d_in[1];
    const float* y0     = (const float*)d_in[2];
    const int num_steps = out_size / NN;

    nmm_kernel<<<dim3(1), dim3(NT), 0, stream>>>(
        params, Cjk, y0, (float*)d_out, num_steps);
}

// Round 10
// 43320.615 us; speedup vs baseline: 1.5071x; 1.5071x over previous
//
#include <hip/hip_runtime.h>
#include <hip/hip_fp16.h>
#include <cmath>

#define NN   68     // nodes
#define HALF 36     // k-values per K-split lane
#define NPAD 72     // padded half2-words per buffer (2 chunks of 36)
#define NT   136    // 2 threads per node (K-split), 3 waves

// lane XOR 1 within quad via DPP quad_perm [1,0,3,2] -- pure VALU, no LDS
__device__ __forceinline__ float dpp_xor1(float x) {
    return __int_as_float(
        __builtin_amdgcn_mov_dpp(__float_as_int(x), 0xB1, 0xF, 0xF, true));
}

#if __has_builtin(__builtin_amdgcn_exp2f)
#define FAST_EXP2(x) __builtin_amdgcn_exp2f(x)
#else
#define FAST_EXP2(x) exp2f(x)
#endif
#define FAST_RCP(x) __builtin_amdgcn_rcpf(x)

// f16 halves of a packed (E_A, E_B) word -> f32 (v_cvt_f32_f16; fusable
// into v_fma_mix_f32 by the AMDGPU peephole)
__device__ __forceinline__ float lo16f(unsigned w) {
    return __half2float(__ushort_as_half((unsigned short)(w & 0xffffu)));
}
__device__ __forceinline__ float hi16f(unsigned w) {
    return __half2float(__ushort_as_half((unsigned short)(w >> 16)));
}
__device__ __forceinline__ unsigned packh2(float a, float b) {
    __half2 h = __floats2half2_rn(a, b);   // RNE, no systematic bias
    return *reinterpret_cast<unsigned*>(&h);
}

// one uint4 = 4 packed pairs = k-indices 4i..4i+3 of BOTH vectors.
// accA (lo halves) -> conn for step T; accB (hi) -> step T+1.
#define MACH(c, u)                          \
    a0 = fmaf(c.x, lo16f(u.x), a0);         \
    b0 = fmaf(c.x, hi16f(u.x), b0);         \
    a1 = fmaf(c.y, lo16f(u.y), a1);         \
    b1 = fmaf(c.y, hi16f(u.y), b1);         \
    a2 = fmaf(c.z, lo16f(u.z), a2);         \
    b2 = fmaf(c.z, hi16f(u.z), b2);         \
    a3 = fmaf(c.w, lo16f(u.w), a3);         \
    b3 = fmaf(c.w, hi16f(u.w), b3);

// one Euler sub-step (R4-validated fast exp2/rcp math)
#define ELEM(Ein, Iin, CONN, Eout, Iout)                                      \
    {                                                                         \
        const float xE = P1 * (Ein) - P2 * (Iin) + P5 * (CONN) + Pp;          \
        const float Se = FAST_RCP(1.0f + FAST_EXP2(fmaf(kE2, xE, bE2))) - s0E;\
        const float xI = P3 * (Ein) - P4 * (Iin);                             \
        const float Si = FAST_RCP(1.0f + FAST_EXP2(fmaf(kI2, xI, bI2))) - s0I;\
        Eout = fmaf(fmaf(kE - (Ein), Se, -(Ein)), inv_te, (Ein));             \
        Iout = fmaf(fmaf(kI - (Iin), Si, -(Iin)), inv_ti, (Iin));             \
    }

// SUPERSTEP: steps T, T+1, ONE barrier. RBUF holds packed (E_{T-1}, E_T);
// writes packed (E_{T+1}, E_{T+2}) into WBUF. 9 ds_read_b128 per thread
// (half of the f32 version -- the whole point of this round).
#define SUPER(RBUF, WBUF, T)                                                  \
    {                                                                         \
        const uint4* vp = (const uint4*)&(RBUF)[s * HALF];                    \
        const uint4 u0 = vp[0], u1 = vp[1], u2 = vp[2], u3 = vp[3],           \
                    u4 = vp[4], u5 = vp[5], u6 = vp[6], u7 = vp[7],           \
                    u8 = vp[8];                                               \
        float a0=0.f,a1=0.f,a2=0.f,a3=0.f,b0=0.f,b1=0.f,b2=0.f,b3=0.f;        \
        MACH(q0, u0) MACH(q1, u1) MACH(q2, u2) MACH(q3, u3) MACH(q4, u4)      \
        MACH(q5, u5) MACH(q6, u6) MACH(q7, u7) MACH(q8, u8)                   \
        float pA = (a0 + a1) + (a2 + a3);                                     \
        float pB = (b0 + b1) + (b2 + b3);                                     \
        pA += dpp_xor1(pA);            /* both K-lanes: full dot */           \
        pB += dpp_xor1(pB);                                                   \
        float En1, In1, En2, In2;                                             \
        ELEM(E, I, pA, En1, In1)       /* step T   */                         \
        ELEM(En1, In1, pB, En2, In2)   /* step T+1 */                         \
        (WBUF)[j] = packh2(En1, En2);  /* same-addr same-value x2: free */    \
        if (s == 0) *(float2*)(op + (T)) = make_float2(En1 - In1, En2 - In2); \
        E = En2; I = In2;                                                     \
        asm volatile("s_waitcnt lgkmcnt(0)\ns_barrier" ::: "memory");         \
    }

__global__ __launch_bounds__(NT, 1)
void nmm_kernel(const float* __restrict__ params,
                const float* __restrict__ Cjk,
                const float* __restrict__ y0,
                float* __restrict__ out,
                const int num_steps)
{
#pragma clang fp contract(off)
    const int tid = threadIdx.x;
    const int j   = tid >> 1;    // node 0..67
    const int s   = tid & 1;     // K-half 0/1

    // packed (older E, newer E) f16 pairs, double-buffered
    __shared__ __align__(16) unsigned Pb0[NPAD], Pb1[NPAD];

    const float tau_e = params[0], tau_i = params[1];
    const float P1 = params[2], P2 = params[3], P3 = params[4];
    const float P4 = params[5], P5 = params[6], Pp = params[7];
    const float kE = params[8], kI = params[9];

    const float LOG2E = 1.4426950408889634f;
    const float kE2 = -1.3f * LOG2E, bE2 = (1.3f * 4.0f) * LOG2E;
    const float kI2 = -2.0f * LOG2E, bI2 = (2.0f * 3.7f) * LOG2E;
    const float s0E = 1.0f / (1.0f + expf(5.2f));
    const float s0I = 1.0f / (1.0f + expf(7.4f));
    const float inv_te = 1.0f / tau_e, inv_ti = 1.0f / tau_i;

    // C-row half chunk -> 9 f32 quads (exact); s=1 top quad is zero pad
    const float* crow = Cjk + j * NN + s * HALF;
    const float4 q0 = *(const float4*)(crow +  0);
    const float4 q1 = *(const float4*)(crow +  4);
    const float4 q2 = *(const float4*)(crow +  8);
    const float4 q3 = *(const float4*)(crow + 12);
    const float4 q4 = *(const float4*)(crow + 16);
    const float4 q5 = *(const float4*)(crow + 20);
    const float4 q6 = *(const float4*)(crow + 24);
    const float4 q7 = *(const float4*)(crow + 28);
    const float4 q8 = (s == 0) ? *(const float4*)(crow + 32)
                               : make_float4(0.f, 0.f, 0.f, 0.f);

    // init: reference steps 0 AND 1 both use C@E_0 -> pairs (E0, E0);
    // pads 68..71 zero in both buffers, never written again
    if (tid < NPAD) {
        const float v = (tid < NN) ? y0[tid] : 0.0f;
        Pb0[tid] = packh2(v, v);
        Pb1[tid] = 0u;
    }
    float E = y0[j];
    float I = y0[NN + j];
    asm volatile("s_waitcnt lgkmcnt(0)\ns_barrier" ::: "memory");

    float* op = out + (size_t)j * (size_t)num_steps;

    int t = 0;
    for (; t + 3 < num_steps; t += 4) {
        SUPER(Pb0, Pb1, t)
        SUPER(Pb1, Pb0, t + 2)
    }
    // generic tails (dead for num_steps % 4 == 0, kept for correctness)
    bool rb1 = false;
    if (t + 1 < num_steps) {
        SUPER(Pb0, Pb1, t)
        t += 2; rb1 = true;
    }
    if (t < num_steps) {   // final odd step: conn = C @ lo-halves (E_{t-1})
        const unsigned* R = rb1 ? Pb1 : Pb0;
        const uint4* vp = (const uint4*)&R[s * HALF];
        const uint4 u0 = vp[0], u1 = vp[1], u2 = vp[2], u3 = vp[3],
                    u4 = vp[4], u5 = vp[5], u6 = vp[6], u7 = vp[7],
                    u8 = vp[8];
        float a0 = 0.f, a1 = 0.f, a2 = 0.f, a3 = 0.f;
#define MACL(c, u)                          \
        a0 = fmaf(c.x, lo16f(u.x), a0);     \
        a1 = fmaf(c.y, lo16f(u.y), a1);     \
        a2 = fmaf(c.z, lo16f(u.z), a2);     \
        a3 = fmaf(c.w, lo16f(u.w), a3);
        MACL(q0, u0) MACL(q1, u1) MACL(q2, u2) MACL(q3, u3) MACL(q4, u4)
        MACL(q5, u5) MACL(q6, u6) MACL(q7, u7) MACL(q8, u8)
#undef MACL
        float pA = (a0 + a1) + (a2 + a3);
        pA += dpp_xor1(pA);
        float En1, In1;
        ELEM(E, I, pA, En1, In1)
        if (s == 0) op[t] = En1 - In1;
    }
}

extern "C" void kernel_launch(void* const* d_in, const int* in_sizes, int n_in,
                              void* d_out, int out_size, void* d_ws, size_t ws_size,
                              hipStream_t stream) {
    const float* params = (const float*)d_in[0];
    const float* Cjk    = (const float*)d_in[1];
    const float* y0     = (const float*)d_in[2];
    const int num_steps = out_size / NN;

    nmm_kernel<<<dim3(1), dim3(NT), 0, stream>>>(
        params, Cjk, y0, (float*)d_out, num_steps);
}